// Round 1
// baseline (169.313 us; speedup 1.0000x reference)
//
#include <hip/hip_runtime.h>
#include <hip/hip_bf16.h>

// Contrastive loss: N=4096 samples, V=2 views, D=256.
// M = V*N = 8192 view-major rows. loss = mean_i [ log sum_{j!=i} exp(l_ij/T) - l_{i,pos}/T ]
// l = normalize(A_vm) @ normalize(B_vm)^T, pos(i) = (i+N) mod M.

#define N_SAMP 4096
#define DIM    256
#define M_ROWS 8192
#define BM 128
#define BN 128
#define BK 64

using short8 = __attribute__((ext_vector_type(8))) short;
using f32x4  = __attribute__((ext_vector_type(4))) float;

// ---------------------------------------------------------------------------
// Normalize rows (view-major) and cast to bf16.  One wave per output row.
// out row m: v = m>>12, n = m&4095; input offset (n*2+v)*256.
// ---------------------------------------------------------------------------
__global__ __launch_bounds__(256) void norm_kernel(
    const float* __restrict__ A, const float* __restrict__ B,
    unsigned short* __restrict__ Ah, unsigned short* __restrict__ Bh)
{
  int tid  = threadIdx.x;
  int wave = tid >> 6, lane = tid & 63;
  int gw   = blockIdx.x * 4 + wave;          // 0 .. 2*M-1
  const float* src; unsigned short* dst; int m;
  if (gw < M_ROWS) { src = A; dst = Ah; m = gw; }
  else             { src = B; dst = Bh; m = gw - M_ROWS; }
  int n = m & (N_SAMP - 1);
  int v = m >> 12;
  const float4* in = (const float4*)(src + (size_t)(n * 2 + v) * DIM);
  float4 x = in[lane];                       // 16B/lane, coalesced
  float ss = x.x*x.x + x.y*x.y + x.z*x.z + x.w*x.w;
  #pragma unroll
  for (int d = 1; d < 64; d <<= 1) ss += __shfl_xor(ss, d);
  float scale = 1.0f / fmaxf(sqrtf(ss), 1e-12f);
  float vals[4] = {x.x*scale, x.y*scale, x.z*scale, x.w*scale};
  ushort4 o;
  unsigned short* op = (unsigned short*)&o;
  #pragma unroll
  for (int k = 0; k < 4; ++k) {              // f32 -> bf16 RNE
    unsigned int u = __float_as_uint(vals[k]);
    u += 0x7fffu + ((u >> 16) & 1u);
    op[k] = (unsigned short)(u >> 16);
  }
  *(ushort4*)(dst + (size_t)m * DIM + lane * 4) = o;
}

// ---------------------------------------------------------------------------
// 128x128-tile bf16 MFMA GEMM (NT: C[i][j] = dot(Ah[i], Bh[j])) with fused
// exp-sum epilogue. m97 structure: global_load_lds(16B) staging, XOR-swizzled
// source + swizzled ds_read_b128 (both-sides involution), 2-barrier K loop.
// ---------------------------------------------------------------------------
__global__ __launch_bounds__(256) void gemm_lse_kernel(
    const unsigned short* __restrict__ Ah, const unsigned short* __restrict__ Bh,
    float* __restrict__ S, float* __restrict__ Pos)
{
  __shared__ alignas(16) char lds[2 * BM * BK * 2];   // As 16KB | Bs 16KB
  char* As = lds;
  char* Bs = lds + BM * BK * 2;

  int tid  = threadIdx.x;
  int lane = tid & 63;
  int w    = tid >> 6;
  int wrow = w >> 1, wcol = w & 1;           // 2x2 wave grid, 64x64 each
  int bi = blockIdx.y, bj = blockIdx.x;
  int row0 = bi * BM, col0 = bj * BN;

  f32x4 acc[4][4];
  #pragma unroll
  for (int i = 0; i < 4; ++i)
    #pragma unroll
    for (int j = 0; j < 4; ++j)
      acc[i][j] = (f32x4){0.f, 0.f, 0.f, 0.f};

  // staging: thread t -> row (is*32 + t>>3), 16B chunk (t&7), source chunk
  // XOR-swizzled so linear LDS dest + swizzled read = consistent involution.
  int srcChunkOff = (((tid & 7) ^ ((tid >> 3) & 7)) * 16);  // bytes in 128B row
  int ldsOff = tid * 16;

  for (int k0 = 0; k0 < DIM; k0 += BK) {
    #pragma unroll
    for (int is = 0; is < 4; ++is) {
      int r = is * 32 + (tid >> 3);
      const char* gA = (const char*)(Ah + (size_t)(row0 + r) * DIM + k0) + srcChunkOff;
      const char* gB = (const char*)(Bh + (size_t)(col0 + r) * DIM + k0) + srcChunkOff;
      __builtin_amdgcn_global_load_lds(
          (const __attribute__((address_space(1))) void*)gA,
          (__attribute__((address_space(3))) void*)(As + is * 4096 + ldsOff), 16, 0, 0);
      __builtin_amdgcn_global_load_lds(
          (const __attribute__((address_space(1))) void*)gB,
          (__attribute__((address_space(3))) void*)(Bs + is * 4096 + ldsOff), 16, 0, 0);
    }
    __syncthreads();

    #pragma unroll
    for (int kk = 0; kk < 2; ++kk) {
      short8 a[4], b[4];
      int ac = kk * 4 + (lane >> 4);                    // k-chunk 0..7
      #pragma unroll
      for (int f = 0; f < 4; ++f) {
        int ar = wrow * 64 + f * 16 + (lane & 15);
        a[f] = *(const short8*)(As + ar * 128 + ((ac ^ (ar & 7)) * 16));
        int br = wcol * 64 + f * 16 + (lane & 15);
        b[f] = *(const short8*)(Bs + br * 128 + ((ac ^ (br & 7)) * 16));
      }
      #pragma unroll
      for (int i = 0; i < 4; ++i)
        #pragma unroll
        for (int j = 0; j < 4; ++j)
          acc[i][j] = __builtin_amdgcn_mfma_f32_16x16x32_bf16(a[i], b[j], acc[i][j], 0, 0, 0);
    }
    __syncthreads();
  }

  // epilogue: S_i += sum_j exp(l/T), skip diagonal, record positive.
  const float KE = (float)(1.4426950408889634 / 0.07);  // log2(e)/T
  #pragma unroll
  for (int i = 0; i < 4; ++i) {
    #pragma unroll
    for (int r = 0; r < 4; ++r) {
      int gi = row0 + wrow * 64 + i * 16 + (lane >> 4) * 4 + r;
      float psum = 0.f;
      #pragma unroll
      for (int j = 0; j < 4; ++j) {
        int gj = col0 + wcol * 64 + j * 16 + (lane & 15);
        float l = acc[i][j][r];
        float e = exp2f(l * KE);
        if (((gi ^ gj) & (N_SAMP - 1)) == 0) {   // same sample index
          if (gi == gj) e = 0.f;                 // diagonal excluded
          else Pos[gi] = l;                      // unique positive per row
        }
        psum += e;
      }
      #pragma unroll
      for (int d = 1; d < 16; d <<= 1) psum += __shfl_xor(psum, d);
      if ((lane & 15) == 0) atomicAdd(&S[gi], psum);
    }
  }
}

// ---------------------------------------------------------------------------
// loss = mean_i ( log S_i - Pos_i / T )
// ---------------------------------------------------------------------------
__global__ __launch_bounds__(256) void reduce_kernel(
    const float* __restrict__ S, const float* __restrict__ Pos,
    float* __restrict__ out)
{
  __shared__ float wsum[4];
  int tid = threadIdx.x;
  const float INVT = 1.0f / 0.07f;
  float acc = 0.f;
  for (int i = tid; i < M_ROWS; i += 256)
    acc += logf(S[i]) - Pos[i] * INVT;
  #pragma unroll
  for (int d = 1; d < 64; d <<= 1) acc += __shfl_xor(acc, d);
  if ((tid & 63) == 0) wsum[tid >> 6] = acc;
  __syncthreads();
  if (tid == 0)
    out[0] = (wsum[0] + wsum[1] + wsum[2] + wsum[3]) / (float)M_ROWS;
}

extern "C" void kernel_launch(void* const* d_in, const int* in_sizes, int n_in,
                              void* d_out, int out_size, void* d_ws, size_t ws_size,
                              hipStream_t stream)
{
  const float* A = (const float*)d_in[0];
  const float* B = (const float*)d_in[1];
  char* ws = (char*)d_ws;
  unsigned short* Ah = (unsigned short*)ws;                                  // 4 MB
  unsigned short* Bh = (unsigned short*)(ws + (size_t)M_ROWS * DIM * 2);     // 4 MB
  float* S   = (float*)(ws + 2 * (size_t)M_ROWS * DIM * 2);                  // 32 KB
  float* Pos = S + M_ROWS;                                                   // 32 KB

  hipMemsetAsync(S, 0, M_ROWS * sizeof(float), stream);
  norm_kernel<<<dim3(2 * M_ROWS / 4), 256, 0, stream>>>(A, B, Ah, Bh);
  gemm_lse_kernel<<<dim3(M_ROWS / BN, M_ROWS / BM), 256, 0, stream>>>(Ah, Bh, S, Pos);
  reduce_kernel<<<1, 256, 0, stream>>>(S, Pos, (float*)d_out);
}

// Round 3
// 123.405 us; speedup vs baseline: 1.3720x; 1.3720x over previous
//
#include <hip/hip_runtime.h>
#include <hip/hip_bf16.h>

// Contrastive loss: N=4096, V=2, D=256.  M=8192 view-major rows.
// loss = mean_i [ log sum_{j!=i} exp(l_ij/T) - l_{i,pos}/T ],  l = norm(A)@norm(B)^T.
// GEMM: A-resident structure. 256 blocks (1/CU), 512 thr. Block = 128 rows x 2048 cols.
// A tile (128x256 bf16 = 64KB) staged to LDS once; B streamed in 32KB K-step chunks,
// double-buffered with counted vmcnt(4) (T3/T4). Fused exp-sum epilogue per coltile,
// register-accumulated row sums, one atomic per row per wave at the end.

#define N_SAMP 4096
#define DIM    256
#define M_ROWS 8192

using short8 = __attribute__((ext_vector_type(8))) short;
using f32x4  = __attribute__((ext_vector_type(4))) float;

#define GLDS(g, l) __builtin_amdgcn_global_load_lds( \
    (const __attribute__((address_space(1))) void*)(g), \
    (__attribute__((address_space(3))) void*)(l), 16, 0, 0)

// ---------------------------------------------------------------------------
// Normalize rows (view-major) -> bf16; also zero S (first 8 blocks).
// ---------------------------------------------------------------------------
__global__ __launch_bounds__(256) void norm_kernel(
    const float* __restrict__ A, const float* __restrict__ B,
    unsigned short* __restrict__ Ah, unsigned short* __restrict__ Bh,
    float* __restrict__ S)
{
  int tid = threadIdx.x;
  if (blockIdx.x < 8)
    ((float4*)S)[blockIdx.x * 256 + tid] = (float4){0.f, 0.f, 0.f, 0.f};

  int wave = tid >> 6, lane = tid & 63;
  int gw   = blockIdx.x * 4 + wave;          // 0 .. 2*M-1
  const float* src; unsigned short* dst; int m;
  if (gw < M_ROWS) { src = A; dst = Ah; m = gw; }
  else             { src = B; dst = Bh; m = gw - M_ROWS; }
  int n = m & (N_SAMP - 1);
  int v = m >> 12;
  const float4* in = (const float4*)(src + (size_t)(n * 2 + v) * DIM);
  float4 x = in[lane];
  float ss = x.x*x.x + x.y*x.y + x.z*x.z + x.w*x.w;
  #pragma unroll
  for (int d = 1; d < 64; d <<= 1) ss += __shfl_xor(ss, d);
  float scale = 1.0f / fmaxf(sqrtf(ss), 1e-12f);
  float vals[4] = {x.x*scale, x.y*scale, x.z*scale, x.w*scale};
  ushort4 o;
  unsigned short* op = (unsigned short*)&o;
  #pragma unroll
  for (int k = 0; k < 4; ++k) {              // f32 -> bf16 RNE
    unsigned int u = __float_as_uint(vals[k]);
    u += 0x7fffu + ((u >> 16) & 1u);
    op[k] = (unsigned short)(u >> 16);
  }
  *(ushort4*)(dst + (size_t)m * DIM + lane * 4) = o;
}

// ---------------------------------------------------------------------------
// A-resident GEMM + fused LSE-sum epilogue.
// ---------------------------------------------------------------------------
__global__ __launch_bounds__(512, 2) void gemm_lse_kernel(
    const unsigned short* __restrict__ Ah, const unsigned short* __restrict__ Bh,
    float* __restrict__ S, float* __restrict__ Pos)
{
  __shared__ alignas(16) char lds[65536 + 2 * 32768];   // As 64KB | Bs0 | Bs1
  char* As  = lds;
  char* Bs0 = lds + 65536;
  char* Bs1 = lds + 65536 + 32768;

  int tid  = threadIdx.x;
  int lane = tid & 63;
  int w    = tid >> 6;
  int wrow = w >> 2, wcol = w & 3;           // 2x4 wave grid, 64x64 each
  int row0 = blockIdx.y * 128;
  int col0 = blockIdx.x * 2048;

  // ---- prologue: stage full A tile (8 shots x 16B/thread), swizzled source.
  #pragma unroll
  for (int s = 0; s < 8; ++s) {
    int f = s * 512 + tid;
    int r = f >> 5, cd = f & 31;             // row 0..127, 16B chunk 0..31
    int cs = cd ^ (r & 7);
    GLDS((const char*)Ah + (size_t)(row0 + r) * 512 + cs * 16, As + f * 16);
  }
  // B stage: tile t = (coltile ct, kstep ks); 4 shots x 16B/thread.
  auto stageB = [&](int t, char* Bbuf) {
    int ct = t >> 2, ks = t & 3;
    const char* base = (const char*)Bh + (size_t)(col0 + ct * 256) * 512 + ks * 128;
    #pragma unroll
    for (int s = 0; s < 4; ++s) {
      int f = s * 512 + tid;
      int r = f >> 3, cd = f & 7;            // col-row 0..255, chunk 0..7
      int cs = cd ^ (r & 7);
      GLDS(base + (size_t)r * 512 + cs * 16, Bbuf + f * 16);
    }
  };
  stageB(0, Bs0);

  f32x4 acc[4][4];
  float ssum[4][4];
  #pragma unroll
  for (int i = 0; i < 4; ++i)
    #pragma unroll
    for (int r = 0; r < 4; ++r) ssum[i][r] = 0.f;

  const float KE = (float)(1.4426950408889634 / 0.07);  // log2(e)/T

  for (int t = 0; t < 32; ++t) {
    char* Bcur = (t & 1) ? Bs1 : Bs0;
    char* Bnxt = (t & 1) ? Bs0 : Bs1;
    if (t < 31) {
      stageB(t + 1, Bnxt);
      asm volatile("s_waitcnt vmcnt(4)" ::: "memory");  // cur tile (+A) done; next 4 in flight
    } else {
      asm volatile("s_waitcnt vmcnt(0)" ::: "memory");
    }
    __builtin_amdgcn_s_barrier();

    int ks = t & 3;
    if (ks == 0) {
      #pragma unroll
      for (int i = 0; i < 4; ++i)
        #pragma unroll
        for (int j = 0; j < 4; ++j)
          acc[i][j] = (f32x4){0.f, 0.f, 0.f, 0.f};
    }

    #pragma unroll
    for (int kk = 0; kk < 2; ++kk) {
      short8 a[4], b[4];
      int ca = ks * 8 + kk * 4 + (lane >> 4);
      int cb = kk * 4 + (lane >> 4);
      #pragma unroll
      for (int f = 0; f < 4; ++f) {
        int ar = wrow * 64 + f * 16 + (lane & 15);
        a[f] = *(const short8*)(As + ar * 512 + ((ca ^ (ar & 7)) * 16));
        int br = wcol * 64 + f * 16 + (lane & 15);
        b[f] = *(const short8*)(Bcur + br * 128 + ((cb ^ (br & 7)) * 16));
      }
      #pragma unroll
      for (int i = 0; i < 4; ++i)
        #pragma unroll
        for (int j = 0; j < 4; ++j)
          acc[i][j] = __builtin_amdgcn_mfma_f32_16x16x32_bf16(a[i], b[j], acc[i][j], 0, 0, 0);
    }

    if (ks == 3) {                           // coltile done: fused epilogue
      int ct = t >> 2;
      #pragma unroll
      for (int i = 0; i < 4; ++i) {
        #pragma unroll
        for (int j = 0; j < 4; ++j) {
          int gj = col0 + ct * 256 + wcol * 64 + j * 16 + (lane & 15);
          #pragma unroll
          for (int r = 0; r < 4; ++r) {
            int gi = row0 + wrow * 64 + i * 16 + (lane >> 4) * 4 + r;
            float l = acc[i][j][r];
            float e = exp2f(l * KE);
            if (((gi ^ gj) & (N_SAMP - 1)) == 0) {
              if (gi == gj) e = 0.f;         // diagonal excluded
              else Pos[gi] = l;              // unique positive per row
            }
            ssum[i][r] += e;
          }
        }
      }
    }
    __builtin_amdgcn_s_barrier();
  }

  // ---- final: reduce ssum across the 16 lanes sharing each row, one atomic.
  #pragma unroll
  for (int i = 0; i < 4; ++i) {
    #pragma unroll
    for (int r = 0; r < 4; ++r) {
      float v = ssum[i][r];
      v += __shfl_xor(v, 1);
      v += __shfl_xor(v, 2);
      v += __shfl_xor(v, 4);
      v += __shfl_xor(v, 8);
      if ((lane & 15) == 0) {
        int gi = row0 + wrow * 64 + i * 16 + (lane >> 4) * 4 + r;
        atomicAdd(&S[gi], v);
      }
    }
  }
}

// ---------------------------------------------------------------------------
// loss = mean_i ( log S_i - Pos_i / T )
// ---------------------------------------------------------------------------
__global__ __launch_bounds__(1024) void reduce_kernel(
    const float* __restrict__ S, const float* __restrict__ Pos,
    float* __restrict__ out)
{
  __shared__ float wsum[16];
  int tid = threadIdx.x;
  const float INVT = 1.0f / 0.07f;
  const float4* S4 = (const float4*)S;
  const float4* P4 = (const float4*)Pos;
  float acc = 0.f;
  #pragma unroll
  for (int q = 0; q < 2; ++q) {              // 8 rows per thread
    float4 s = S4[tid * 2 + q];
    float4 p = P4[tid * 2 + q];
    acc += logf(s.x) - p.x * INVT;
    acc += logf(s.y) - p.y * INVT;
    acc += logf(s.z) - p.z * INVT;
    acc += logf(s.w) - p.w * INVT;
  }
  #pragma unroll
  for (int d = 1; d < 64; d <<= 1) acc += __shfl_xor(acc, d);
  if ((tid & 63) == 0) wsum[tid >> 6] = acc;
  __syncthreads();
  if (tid == 0) {
    float t = 0.f;
    #pragma unroll
    for (int k = 0; k < 16; ++k) t += wsum[k];
    out[0] = t / (float)M_ROWS;
  }
}

extern "C" void kernel_launch(void* const* d_in, const int* in_sizes, int n_in,
                              void* d_out, int out_size, void* d_ws, size_t ws_size,
                              hipStream_t stream)
{
  const float* A = (const float*)d_in[0];
  const float* B = (const float*)d_in[1];
  char* ws = (char*)d_ws;
  unsigned short* Ah = (unsigned short*)ws;                                  // 4 MB
  unsigned short* Bh = (unsigned short*)(ws + (size_t)M_ROWS * DIM * 2);     // 4 MB
  float* S   = (float*)(ws + 2 * (size_t)M_ROWS * DIM * 2);                  // 32 KB
  float* Pos = S + M_ROWS;                                                   // 32 KB

  norm_kernel<<<dim3(2 * M_ROWS / 4), 256, 0, stream>>>(A, B, Ah, Bh, S);
  gemm_lse_kernel<<<dim3(4, 64), 512, 0, stream>>>(Ah, Bh, S, Pos);
  reduce_kernel<<<1, 1024, 0, stream>>>(S, Pos, (float*)d_out);
}